// Round 1
// 353.928 us; speedup vs baseline: 1.0098x; 1.0098x over previous
//
#include <hip/hip_runtime.h>

// KVCacheManager: out[0] = transpose(K[:, :, :, :S]) (B,H,D,S)->(B,H,S,D)
//                 out[1] = V[:, :, :S, :] contiguous copy
// Pure data movement, fp32. Roofline ~402 MB @ ~6.3 TB/s ~= 64 us.
//
// Round 3: stage-1 via global_load_lds (dwordx4 DMA, no VGPR roundtrip,
//   no ds_write instructions). LDS laid out as float4 slots [d][32] with
//   XOR swizzle col' = s4 ^ (d>>2) applied on the GLOBAL SOURCE address
//   (linear LDS dest -- global_load_lds writes base + lane*16 only) and
//   the SAME involution on the stage-2 read. Stage-2 banks: 2-way (free).
//   LDS 33 KB -> 32 KB => 5 blocks/CU.
// V part: 4x-batched non-temporal float4 copy (explicit MLP).

#define BH 32          // B*H = 4*8
#define DD 128         // head dim

typedef float f4 __attribute__((ext_vector_type(4)));

__device__ __forceinline__ void gload_lds16(const float* g, float* l) {
    __builtin_amdgcn_global_load_lds(
        (const __attribute__((address_space(1))) void*)g,
        (__attribute__((address_space(3))) void*)l,
        16, 0, 0);
}

__global__ __launch_bounds__(256) void kv_repack(
    const float* __restrict__ kc, const float* __restrict__ vc,
    float* __restrict__ out,
    int S, int Sfull, int kBlocks, int vBlocksPerBH, int f4PerVBlock)
{
    __shared__ float lds[64 * DD];   // 32,768 B, float4-slot layout [d][32]

    const int bid = blockIdx.x;
    const int t = threadIdx.x;

    if (bid < kBlocks) {
        // ---- K transpose: one block = 64(d) x 128(s) tile ----
        const int sTiles = S >> 7;              // S/128 = 48
        const int perBH  = 2 * sTiles;          // 2 d-tiles
        const int bh     = bid / perBH;
        const int rem    = bid - bh * perBH;
        const int dTile  = rem / sTiles;        // 0 or 1 (64-wide d halves)
        const int sTile  = rem - dTile * sTiles;

        const int wave = t >> 6;                // 0..3
        const int lane = t & 63;

        // stage 1: global -> LDS DMA. Wave covers rows {dbase, dbase+1},
        // 32 f4-slots each; LDS dest linear (dbase*512B + lane*16B); the
        // source column is pre-swizzled so LDS holds [d][c] = K[d][c ^ (d>>2)].
        {
            const float* rowbase = kc
                + (size_t)(bh * DD + dTile * 64) * (size_t)Sfull
                + (size_t)(sTile << 7);
            const int c  = lane & 31;           // f4 slot within row
            const int dh = lane >> 5;           // 0..1
#pragma unroll
            for (int i = 0; i < 8; ++i) {
                const int dbase = (wave << 4) + (i << 1);   // 16w + 2i
                const int d  = dbase + dh;                  // 0..63
                const int s4 = c ^ (d >> 2);                // source swizzle
                gload_lds16(rowbase + (size_t)d * Sfull + (s4 << 2),
                            &lds[dbase << 7]);
            }
        }
        __syncthreads();

        // stage 2: LDS -> global. Element (d', sr) lives at
        // lds[d'*128 + 4*((sr>>2) ^ (d'>>2)) + (sr&3)]; for d' = 4*d4+k the
        // swizzle term is d4 for all k => one column addr + 3 imm offsets.
        // Banks: 4*((4i+w)^d4)+q spans all 32 per wave => 2-way (free).
        {
            const int d4 = t & 15;              // float4 column in d (64-wide)
            const int r0 = t >> 4;              // 0..15
            float* dstBase = out
                + ((size_t)bh * S + (size_t)(sTile << 7)) * DD
                + dTile * 64 + (d4 << 2);
#pragma unroll
            for (int i = 0; i < 8; ++i) {
                const int sr  = (i << 4) + r0;  // 0..127
                const int col = (((sr >> 2) ^ d4) << 2) + (sr & 3);
                const int base = (d4 << 9) + col;   // (4*d4)*128 + col
                f4 v;
                v.x = lds[base];
                v.y = lds[base + DD];
                v.z = lds[base + 2 * DD];
                v.w = lds[base + 3 * DD];
                __builtin_nontemporal_store(v, (f4*)(dstBase + (size_t)sr * DD));
            }
        }
    } else {
        // ---- V copy: contiguous float4 chunk copy per (b,h), MLP=4 ----
        const int vb   = bid - kBlocks;
        const int bh   = vb / vBlocksPerBH;
        const int part = vb - bh * vBlocksPerBH;

        const size_t f4PerBHsrc = (size_t)Sfull * (DD / 4);
        const size_t f4PerBHdst = (size_t)S * (DD / 4);
        const size_t outVOff    = (size_t)BH * S * (DD / 4);

        const f4* src = (const f4*)vc + (size_t)bh * f4PerBHsrc
                        + (size_t)part * f4PerVBlock;
        f4* dst = (f4*)out + outVOff + (size_t)bh * f4PerBHdst
                  + (size_t)part * f4PerVBlock;

        const int n = f4PerVBlock;
        int j = t;
        for (; j + 768 < n; j += 1024) {
            f4 a0 = __builtin_nontemporal_load(src + j);
            f4 a1 = __builtin_nontemporal_load(src + j + 256);
            f4 a2 = __builtin_nontemporal_load(src + j + 512);
            f4 a3 = __builtin_nontemporal_load(src + j + 768);
            __builtin_nontemporal_store(a0, dst + j);
            __builtin_nontemporal_store(a1, dst + j + 256);
            __builtin_nontemporal_store(a2, dst + j + 512);
            __builtin_nontemporal_store(a3, dst + j + 768);
        }
        for (; j < n; j += 256) {
            f4 a = __builtin_nontemporal_load(src + j);
            __builtin_nontemporal_store(a, dst + j);
        }
    }
}

extern "C" void kernel_launch(void* const* d_in, const int* in_sizes, int n_in,
                              void* d_out, int out_size, void* d_ws, size_t ws_size,
                              hipStream_t stream) {
    const float* kc = (const float*)d_in[0];
    const float* vc = (const float*)d_in[1];
    float* out = (float*)d_out;

    // Derive shapes host-side: out = (2, B,H, S, D)
    const int S     = out_size / (2 * BH * DD);          // 6144
    const int Sfull = in_sizes[0] / (BH * DD);           // 8192

    const int sTiles        = S >> 7;                    // 48
    const int kBlocks       = BH * 2 * sTiles;           // 3072
    const int vBlocksPerBH  = sTiles;                    // 48
    const int f4PerVBlock   = (S * (DD / 4)) / vBlocksPerBH; // 4096
    const int vBlocks       = BH * vBlocksPerBH;         // 1536

    dim3 grid(kBlocks + vBlocks);
    dim3 block(256);
    kv_repack<<<grid, block, 0, stream>>>(kc, vc, out, S, Sfull,
                                          kBlocks, vBlocksPerBH, f4PerVBlock);
}